// Round 19
// baseline (97.145 us; speedup 1.0000x reference)
//
#include <hip/hip_runtime.h>
#include <hip/hip_fp16.h>
#include <math.h>

// Problem constants
#define BB 256
#define NE 400
#define NP (BB * NE)        // 102400 pairs
#define HID 256
#define NCOP 224
#define DIN 480
#define MBLK 64             // pairs per block in fused MFMA kernel
#define NBLK (NP / MBLK)    // 1600

typedef _Float16 half8 __attribute__((ext_vector_type(8)));
typedef _Float16 half4 __attribute__((ext_vector_type(4)));
typedef float f4 __attribute__((ext_vector_type(4)));

// Native f32 silu (round 13): used where precision feeds the output dot.
static __device__ __forceinline__ float silu_f(float x) {
    float e = __builtin_amdgcn_exp2f(x * -1.44269504088896340736f);
    return x * __builtin_amdgcn_rcpf(1.0f + e);
}

// Packed-f16 silu: v_pk ops + v_exp_f16/v_rcp_f16 (trans). ~40% fewer VALU
// ops than the f32 path per element. Limits: x<<0 -> e=inf -> rcp=0 -> 0;
// x>>0 -> e=0 -> x. Error ~1-2 ulp f16 on values that are f16-stored anyway.
static __device__ __forceinline__ __half2 silu_h2(__half2 x) {
    __half2 e = h2exp(__hneg2(x));
    __half2 d = __hadd2(e, __float2half2_rn(1.0f));
    return __hmul2(x, h2rcp(d));
}

// Swizzled byte offset into one 32 KB activation buffer.
static __device__ __forceinline__ int swz(int row, int colbyte) {
    return (row * 512 + colbyte) ^ ((row & 7) << 4);
}

// ---------------------------------------------------------------------------
// Precompute (fp32): E1/F1/Fo/S as before.
// ---------------------------------------------------------------------------
__global__ void precompute_kernel(const float* __restrict__ h_abs,
                                  const float* __restrict__ e_feat,
                                  const float* __restrict__ field,
                                  const float* __restrict__ mW1,
                                  const float* __restrict__ mb1,
                                  const float* __restrict__ oW1,
                                  const float* __restrict__ ob1,
                                  float* __restrict__ E1,
                                  float* __restrict__ F1,
                                  float* __restrict__ Fo,
                                  float* __restrict__ S)
{
    int r = blockIdx.x;
    int t = threadIdx.x;
    if (r < NE) {
        float a = 0.f;
        #pragma unroll
        for (int k = 0; k < 32; ++k) a += e_feat[r * 32 + k] * mW1[k * HID + t];
        E1[r * HID + t] = a;
    } else if (r < NE + BB) {
        int b = r - NE;
        float a = mb1[t];
        #pragma unroll
        for (int k = 0; k < 64; ++k) a += field[b * 64 + k] * mW1[(32 + k) * HID + t];
        F1[b * HID + t] = a;
    } else if (r < NE + 2 * BB) {
        int b = r - NE - BB;
        float a = ob1[t];
        #pragma unroll
        for (int k = 0; k < 64; ++k) a += field[b * 64 + k] * oW1[(224 + k) * HID + t];
        Fo[b * HID + t] = a;
    } else {
        int b = r - NE - 2 * BB;
        if (t < 64) {
            const float* x = h_abs + b * DIN + 128 + t * 3;
            S[b * 96 + t] = (x[0]*x[0] + x[1]*x[1] + x[2]*x[2]) * (1.0f / 3.0f);
        } else if (t < 96) {
            int c = t - 64;
            const float* x = h_abs + b * DIN + 320 + c * 5;
            float s = 0.f;
            #pragma unroll
            for (int d = 0; d < 5; ++d) s += x[d] * x[d];
            S[b * 96 + t] = s * 0.2f;
        }
    }
}

// ---------------------------------------------------------------------------
// Pack weights (fp32 -> fp16) into MFMA A-operand fragment order.
// ---------------------------------------------------------------------------
__global__ void pack_weights(const float* __restrict__ mW2, const float* __restrict__ mW3,
                             const float* __restrict__ oW1, const float* __restrict__ oW2,
                             _Float16* __restrict__ PB2, _Float16* __restrict__ PB3,
                             _Float16* __restrict__ PO1, _Float16* __restrict__ PO2)
{
    int blk = blockIdx.x;
    int l = threadIdx.x;
    const float* W; _Float16* P; int LD;
    if (blk < 128)      { W = mW2; P = PB2; LD = 256; }
    else if (blk < 240) { blk -= 128; W = mW3; P = PB3; LD = 224; }
    else if (blk < 352) { blk -= 240; W = oW1; P = PO1; LD = 256; }
    else                { blk -= 352; W = oW2; P = PO2; LD = 256; }
    int KST = (P == PO1) ? 7 : 8;
    int nt = blk / KST, ks = blk - nt * KST;
    int n  = nt * 16 + (l & 15);
    int k0 = ks * 32 + (l >> 4) * 8;
    half8 v;
    #pragma unroll
    for (int j = 0; j < 8; ++j) v[j] = (_Float16)W[(size_t)(k0 + j) * LD + n];
    *(half8*)&P[(size_t)(blk * 64 + l) * 8] = v;
}

// ---------------------------------------------------------------------------
// One GEMM phase on the matrix pipe, operands swapped:
//   acc = mfma(W_frag /*A: rows=n*/, act_frag /*B: cols=pair*/, acc)
// Weight fragments hoisted up-front; acc caller-initialized (bias folded).
// ---------------------------------------------------------------------------
template<int KST, bool TWO>
static __device__ __forceinline__ void mma_phase(const half8* __restrict__ Wp,
                                                 const char* actp, int lane,
                                                 int tile0, f4 acc[4][2])
{
    half8 bf0[KST], bf1[TWO ? KST : 1];
    #pragma unroll
    for (int ks = 0; ks < KST; ++ks)
        bf0[ks] = Wp[(tile0 * KST + ks) * 64 + lane];
    if (TWO) {
        #pragma unroll
        for (int ks = 0; ks < KST; ++ks)
            bf1[ks] = Wp[((tile0 + 8) * KST + ks) * 64 + lane];
    }

    #pragma unroll
    for (int ks = 0; ks < KST; ++ks) {
        int kb = ks * 64 + ((lane >> 4) << 4);
        half8 a[4];
        #pragma unroll
        for (int mt = 0; mt < 4; ++mt) {
            int row = mt * 16 + (lane & 15);
            a[mt] = *(const half8*)(actp + ((row * 512 + kb) ^ ((row & 7) << 4)));
        }
        #pragma unroll
        for (int mt = 0; mt < 4; ++mt)
            acc[mt][0] = __builtin_amdgcn_mfma_f32_16x16x32_f16(bf0[ks], a[mt], acc[mt][0], 0, 0, 0);
        if (TWO) {
            #pragma unroll
            for (int mt = 0; mt < 4; ++mt)
                acc[mt][1] = __builtin_amdgcn_mfma_f32_16x16x32_f16(bf1[ks], a[mt], acc[mt][1], 0, 0, 0);
        }
    }
}

// ---------------------------------------------------------------------------
// Fused kernel: 64 pairs / block, 512 threads (8 waves).
// Ping-pong act buffers (5 barriers); bias-folded acc; packed-f16 silu in
// the A/B/D epilogues (E+F and C remain f32 for output accuracy).
// ---------------------------------------------------------------------------
__global__ __launch_bounds__(512, 1)
void fused_mfma(const float* __restrict__ h_abs,
                const float* __restrict__ mb2, const float* __restrict__ mb3,
                const float* __restrict__ ob2,
                const float* __restrict__ oW3, const float* __restrict__ ob3,
                const float* __restrict__ E1, const float* __restrict__ F1,
                const float* __restrict__ Fo, const float* __restrict__ S,
                const half8* __restrict__ PB2, const half8* __restrict__ PB3,
                const half8* __restrict__ PO1, const half8* __restrict__ PO2,
                float* __restrict__ out)
{
    __shared__ char act[2][MBLK * 512];   // 2 x 32 KB f16 activations
    __shared__ float sred[8][64];         // cross-wave partial sums

    const int t    = threadIdx.x;
    const int lane = t & 63;
    const int w    = t >> 6;           // 0..7
    const int p0   = blockIdx.x * MBLK;
    const int lr   = lane & 15;
    const int lq   = lane >> 4;

    const int b0 = p0 / NE;
    const int r0 = p0 - b0 * NE;

    // Preload all per-column constants once (off the critical path).
    const int nA = w * 16 + lq * 4;          // ntj = 0 (tile w, < 8)
    const int nB = (w + 8) * 16 + lq * 4;    // ntj = 1 (tile w+8)
    f4 bmb2[2], bmb3[2], bob2[2], wv3[2];
    bmb2[0] = *(const f4*)&mb2[nA];  bmb2[1] = *(const f4*)&mb2[nB];
    bmb3[0] = *(const f4*)&mb3[nA];
    bmb3[1] = (w < 6) ? *(const f4*)&mb3[nB] : (f4){0.f, 0.f, 0.f, 0.f};
    bob2[0] = *(const f4*)&ob2[nA];  bob2[1] = *(const f4*)&ob2[nB];
    wv3[0]  = *(const f4*)&oW3[nA];  wv3[1]  = *(const f4*)&oW3[nB];

    // ---- Phase A: h1 = silu(E1[e] + F1[b])  -> act0 (packed-f16 silu) ----
    {
        #pragma unroll
        for (int i = 0; i < 4; ++i) {
            int c   = i * 512 + t;
            int row = c >> 5;
            int c0  = (c & 31) * 8;
            int e = r0 + row;
            int b = b0;
            if (e >= NE) { e -= NE; b += 1; }
            const f4* ep = (const f4*)&E1[e * HID + c0];
            const f4* fp = (const f4*)&F1[b * HID + c0];
            f4 s0 = ep[0] + fp[0];
            f4 s1 = ep[1] + fp[1];
            union { __half2 q[4]; half8 v; } u;
            u.q[0] = silu_h2(__floats2half2_rn(s0[0], s0[1]));
            u.q[1] = silu_h2(__floats2half2_rn(s0[2], s0[3]));
            u.q[2] = silu_h2(__floats2half2_rn(s1[0], s1[1]));
            u.q[3] = silu_h2(__floats2half2_rn(s1[2], s1[3]));
            *(half8*)(act[0] + swz(row, c0 * 2)) = u.v;
        }
    }
    __syncthreads();   // (1) h1 visible

    f4 acc[4][2];

    // ---- Phase B: h2 = silu(h1 @ mW2 + mb2)   [read act0 -> write act1] ----
    #pragma unroll
    for (int mt = 0; mt < 4; ++mt) { acc[mt][0] = bmb2[0]; acc[mt][1] = bmb2[1]; }
    mma_phase<8, true>(PB2, act[0], lane, w, acc);
    #pragma unroll
    for (int ntj = 0; ntj < 2; ++ntj) {
        int n0 = ntj ? nB : nA;
        #pragma unroll
        for (int mt = 0; mt < 4; ++mt) {
            int row = mt * 16 + lr;
            union { __half2 q[2]; half4 v; } u;
            u.q[0] = silu_h2(__floats2half2_rn(acc[mt][ntj][0], acc[mt][ntj][1]));
            u.q[1] = silu_h2(__floats2half2_rn(acc[mt][ntj][2], acc[mt][ntj][3]));
            *(half4*)(act[1] + swz(row, n0 * 2)) = u.v;
        }
    }
    __syncthreads();   // (2) h2 visible; everyone past B-reads of act0

    // ---- Phase C: g = h2 @ mW3 + mb3 ; invariant  [read act1 -> write act0] ----
    #pragma unroll
    for (int mt = 0; mt < 4; ++mt) { acc[mt][0] = bmb3[0]; acc[mt][1] = bmb3[1]; }
    if (w < 6) mma_phase<8, true >(PB3, act[1], lane, w, acc);
    else       mma_phase<8, false>(PB3, act[1], lane, w, acc);
    int bmt[4];
    #pragma unroll
    for (int mt = 0; mt < 4; ++mt)
        bmt[mt] = b0 + ((r0 + mt * 16 + lr) >= NE);
    f4 xh[4], sv[4], fo[4][2];
    #pragma unroll
    for (int mt = 0; mt < 4; ++mt)
        xh[mt] = *(const f4*)&h_abs[bmt[mt] * DIN + nA];
    if (w < 6) {
        #pragma unroll
        for (int mt = 0; mt < 4; ++mt)
            sv[mt] = *(const f4*)&S[bmt[mt] * 96 + nA];   // S idx for tile w+8 is nB-128 == nA
    }
    // Prefetch phase-D's Fo acc-init here (hides L2 latency under C epilogue).
    #pragma unroll
    for (int mt = 0; mt < 4; ++mt) {
        fo[mt][0] = *(const f4*)&Fo[bmt[mt] * HID + nA];
        fo[mt][1] = *(const f4*)&Fo[bmt[mt] * HID + nB];
    }
    {
        // ntj=0: tile w (<8) -> scalar passthrough path, always.
        #pragma unroll
        for (int mt = 0; mt < 4; ++mt) {
            int row = mt * 16 + lr;
            half4 hv;
            #pragma unroll
            for (int r = 0; r < 4; ++r)
                hv[r] = (_Float16)(xh[mt][r] * acc[mt][0][r]);
            *(half4*)(act[0] + swz(row, nA * 2)) = hv;
        }
        // ntj=1: tile w+8 (exists iff w<6) -> L2-norm path.
        if (w < 6) {
            #pragma unroll
            for (int mt = 0; mt < 4; ++mt) {
                int row = mt * 16 + lr;
                half4 hv;
                #pragma unroll
                for (int r = 0; r < 4; ++r) {
                    float g = acc[mt][1][r];
                    hv[r] = (_Float16)__builtin_amdgcn_sqrtf(g * g * sv[mt][r] + 1e-8f);
                }
                *(half4*)(act[0] + swz(row, nB * 2)) = hv;
            }
        }
    }
    __syncthreads();   // (3) inv visible; everyone past C-reads of act1

    // ---- Phase D: o1 = silu(inv @ oW1[0:224] + Fo[b])  [read act0 -> write act1] ----
    #pragma unroll
    for (int mt = 0; mt < 4; ++mt) { acc[mt][0] = fo[mt][0]; acc[mt][1] = fo[mt][1]; }
    mma_phase<7, true>(PO1, act[0], lane, w, acc);
    #pragma unroll
    for (int ntj = 0; ntj < 2; ++ntj) {
        int n0 = ntj ? nB : nA;
        #pragma unroll
        for (int mt = 0; mt < 4; ++mt) {
            int row = mt * 16 + lr;
            union { __half2 q[2]; half4 v; } u;
            u.q[0] = silu_h2(__floats2half2_rn(acc[mt][ntj][0], acc[mt][ntj][1]));
            u.q[1] = silu_h2(__floats2half2_rn(acc[mt][ntj][2], acc[mt][ntj][3]));
            *(half4*)(act[1] + swz(row, n0 * 2)) = u.v;
        }
    }
    __syncthreads();   // (4) o1 visible

    // ---- Phase E+F fused: out[p] = silu(o1 @ oW2 + ob2) . oW3 + ob3 ----
    #pragma unroll
    for (int mt = 0; mt < 4; ++mt) { acc[mt][0] = bob2[0]; acc[mt][1] = bob2[1]; }
    mma_phase<8, true>(PO2, act[1], lane, w, acc);
    {
        float partial[4] = {0.f, 0.f, 0.f, 0.f};
        #pragma unroll
        for (int ntj = 0; ntj < 2; ++ntj) {
            #pragma unroll
            for (int mt = 0; mt < 4; ++mt)
                #pragma unroll
                for (int r = 0; r < 4; ++r)
                    partial[mt] += silu_f(acc[mt][ntj][r]) * wv3[ntj][r];
        }
        #pragma unroll
        for (int mt = 0; mt < 4; ++mt) {
            float s = partial[mt];
            s += __shfl_xor(s, 16, 64);
            s += __shfl_xor(s, 32, 64);
            if (lq == 0) sred[w][mt * 16 + lr] = s;
        }
    }
    __syncthreads();   // (5) sred visible
    if (t < 64) {
        float s = ob3[0];
        #pragma unroll
        for (int ww = 0; ww < 8; ++ww) s += sred[ww][t];
        out[p0 + t] = s;
    }
}

extern "C" void kernel_launch(void* const* d_in, const int* in_sizes, int n_in,
                              void* d_out, int out_size, void* d_ws, size_t ws_size,
                              hipStream_t stream) {
    const float* h_abs  = (const float*)d_in[0];
    const float* e_feat = (const float*)d_in[1];
    const float* field  = (const float*)d_in[2];
    const float* mW1 = (const float*)d_in[3];
    const float* mb1 = (const float*)d_in[4];
    const float* mW2 = (const float*)d_in[5];
    const float* mb2 = (const float*)d_in[6];
    const float* mW3 = (const float*)d_in[7];
    const float* mb3 = (const float*)d_in[8];
    const float* oW1 = (const float*)d_in[9];
    const float* ob1 = (const float*)d_in[10];
    const float* oW2 = (const float*)d_in[11];
    const float* ob2 = (const float*)d_in[12];
    const float* oW3 = (const float*)d_in[13];
    const float* ob3 = (const float*)d_in[14];
    float* out = (float*)d_out;

    // Workspace layout
    float* ws = (float*)d_ws;
    float* E1 = ws;                      // 400*256 = 102400 f
    float* F1 = E1 + NE * HID;           // 65536 f
    float* Fo = F1 + BB * HID;           // 65536 f
    float* S  = Fo + BB * HID;           // 24576 f
    _Float16* PB2 = (_Float16*)(S + BB * 96);   // 16*8*64*8 = 65536 h
    _Float16* PB3 = PB2 + 16 * 8 * 64 * 8;      // 14*8*64*8 = 57344 h
    _Float16* PO1 = PB3 + 14 * 8 * 64 * 8;      // 16*7*64*8 = 57344 h
    _Float16* PO2 = PO1 + 16 * 7 * 64 * 8;      // 16*8*64*8 = 65536 h

    precompute_kernel<<<NE + 3 * BB, 256, 0, stream>>>(
        h_abs, e_feat, field, mW1, mb1, oW1, ob1, E1, F1, Fo, S);

    pack_weights<<<480, 64, 0, stream>>>(
        mW2, mW3, oW1, oW2, PB2, PB3, PO1, PO2);

    fused_mfma<<<NBLK, 512, 0, stream>>>(
        h_abs, mb2, mb3, ob2, oW3, ob3,
        E1, F1, Fo, S,
        (const half8*)PB2, (const half8*)PB3, (const half8*)PO1, (const half8*)PO2,
        out);
}

// Round 20
// 94.585 us; speedup vs baseline: 1.0271x; 1.0271x over previous
//
#include <hip/hip_runtime.h>
#include <math.h>

// Problem constants
#define BB 256
#define NE 400
#define NP (BB * NE)        // 102400 pairs
#define HID 256
#define NCOP 224
#define DIN 480
#define MBLK 64             // pairs per block in fused MFMA kernel
#define NBLK (NP / MBLK)    // 1600

typedef _Float16 half8 __attribute__((ext_vector_type(8)));
typedef _Float16 half4 __attribute__((ext_vector_type(4)));
typedef float f4 __attribute__((ext_vector_type(4)));

// Native silu: v_mul + v_exp_f32 + v_add + v_rcp_f32 + v_mul (round 13: -12 us).
// Round 19 falsified the packed-f16 variant: exp/rcp f16 run at the same
// transcendental-pipe rate as f32, so "packing" only added cvt ops.
static __device__ __forceinline__ float silu_f(float x) {
    float e = __builtin_amdgcn_exp2f(x * -1.44269504088896340736f);
    return x * __builtin_amdgcn_rcpf(1.0f + e);
}

// Swizzled byte offset into one 32 KB activation buffer.
static __device__ __forceinline__ int swz(int row, int colbyte) {
    return (row * 512 + colbyte) ^ ((row & 7) << 4);
}

// ---------------------------------------------------------------------------
// Precompute (fp32):
//  E1[e][n]  = e_feat[e] @ mW1[0:32]                 (400 x 256)
//  F1[b][n]  = field[b] @ mW1[32:96] + mb1           (256 x 256)
//  Fo[b][n]  = field[b] @ oW1[224:288] + ob1         (256 x 256)
//  S[b][c]   = mean(x^2) per copy: l=1 (c<64, dim3), l=2 (c 64..95, dim5)
// ---------------------------------------------------------------------------
__global__ void precompute_kernel(const float* __restrict__ h_abs,
                                  const float* __restrict__ e_feat,
                                  const float* __restrict__ field,
                                  const float* __restrict__ mW1,
                                  const float* __restrict__ mb1,
                                  const float* __restrict__ oW1,
                                  const float* __restrict__ ob1,
                                  float* __restrict__ E1,
                                  float* __restrict__ F1,
                                  float* __restrict__ Fo,
                                  float* __restrict__ S)
{
    int r = blockIdx.x;
    int t = threadIdx.x;
    if (r < NE) {
        float a = 0.f;
        #pragma unroll
        for (int k = 0; k < 32; ++k) a += e_feat[r * 32 + k] * mW1[k * HID + t];
        E1[r * HID + t] = a;
    } else if (r < NE + BB) {
        int b = r - NE;
        float a = mb1[t];
        #pragma unroll
        for (int k = 0; k < 64; ++k) a += field[b * 64 + k] * mW1[(32 + k) * HID + t];
        F1[b * HID + t] = a;
    } else if (r < NE + 2 * BB) {
        int b = r - NE - BB;
        float a = ob1[t];
        #pragma unroll
        for (int k = 0; k < 64; ++k) a += field[b * 64 + k] * oW1[(224 + k) * HID + t];
        Fo[b * HID + t] = a;
    } else {
        int b = r - NE - 2 * BB;
        if (t < 64) {
            const float* x = h_abs + b * DIN + 128 + t * 3;
            S[b * 96 + t] = (x[0]*x[0] + x[1]*x[1] + x[2]*x[2]) * (1.0f / 3.0f);
        } else if (t < 96) {
            int c = t - 64;
            const float* x = h_abs + b * DIN + 320 + c * 5;
            float s = 0.f;
            #pragma unroll
            for (int d = 0; d < 5; ++d) s += x[d] * x[d];
            S[b * 96 + t] = s * 0.2f;
        }
    }
}

// ---------------------------------------------------------------------------
// Pack weights (fp32 -> fp16) into MFMA A-operand fragment order.
// ---------------------------------------------------------------------------
__global__ void pack_weights(const float* __restrict__ mW2, const float* __restrict__ mW3,
                             const float* __restrict__ oW1, const float* __restrict__ oW2,
                             _Float16* __restrict__ PB2, _Float16* __restrict__ PB3,
                             _Float16* __restrict__ PO1, _Float16* __restrict__ PO2)
{
    int blk = blockIdx.x;
    int l = threadIdx.x;
    const float* W; _Float16* P; int LD;
    if (blk < 128)      { W = mW2; P = PB2; LD = 256; }
    else if (blk < 240) { blk -= 128; W = mW3; P = PB3; LD = 224; }
    else if (blk < 352) { blk -= 240; W = oW1; P = PO1; LD = 256; }
    else                { blk -= 352; W = oW2; P = PO2; LD = 256; }
    int KST = (P == PO1) ? 7 : 8;
    int nt = blk / KST, ks = blk - nt * KST;
    int n  = nt * 16 + (l & 15);
    int k0 = ks * 32 + (l >> 4) * 8;
    half8 v;
    #pragma unroll
    for (int j = 0; j < 8; ++j) v[j] = (_Float16)W[(size_t)(k0 + j) * LD + n];
    *(half8*)&P[(size_t)(blk * 64 + l) * 8] = v;
}

// ---------------------------------------------------------------------------
// One GEMM phase on the matrix pipe, operands swapped:
//   acc = mfma(W_frag /*A: rows=n*/, act_frag /*B: cols=pair*/, acc)
// Weight fragments hoisted up-front; acc caller-initialized (bias folded).
// ---------------------------------------------------------------------------
template<int KST, bool TWO>
static __device__ __forceinline__ void mma_phase(const half8* __restrict__ Wp,
                                                 const char* actp, int lane,
                                                 int tile0, f4 acc[4][2])
{
    half8 bf0[KST], bf1[TWO ? KST : 1];
    #pragma unroll
    for (int ks = 0; ks < KST; ++ks)
        bf0[ks] = Wp[(tile0 * KST + ks) * 64 + lane];
    if (TWO) {
        #pragma unroll
        for (int ks = 0; ks < KST; ++ks)
            bf1[ks] = Wp[((tile0 + 8) * KST + ks) * 64 + lane];
    }

    #pragma unroll
    for (int ks = 0; ks < KST; ++ks) {
        int kb = ks * 64 + ((lane >> 4) << 4);
        half8 a[4];
        #pragma unroll
        for (int mt = 0; mt < 4; ++mt) {
            int row = mt * 16 + (lane & 15);
            a[mt] = *(const half8*)(actp + ((row * 512 + kb) ^ ((row & 7) << 4)));
        }
        #pragma unroll
        for (int mt = 0; mt < 4; ++mt)
            acc[mt][0] = __builtin_amdgcn_mfma_f32_16x16x32_f16(bf0[ks], a[mt], acc[mt][0], 0, 0, 0);
        if (TWO) {
            #pragma unroll
            for (int mt = 0; mt < 4; ++mt)
                acc[mt][1] = __builtin_amdgcn_mfma_f32_16x16x32_f16(bf1[ks], a[mt], acc[mt][1], 0, 0, 0);
        }
    }
}

// ---------------------------------------------------------------------------
// Fused kernel: 64 pairs / block, 512 threads (8 waves).
// PING-PONG act buffers: one barrier per phase (5 total). Bias-folded acc.
// Best configuration found (round 18: 94.4 us; 7.7x over round-1 baseline).
// ---------------------------------------------------------------------------
__global__ __launch_bounds__(512, 1)
void fused_mfma(const float* __restrict__ h_abs,
                const float* __restrict__ mb2, const float* __restrict__ mb3,
                const float* __restrict__ ob2,
                const float* __restrict__ oW3, const float* __restrict__ ob3,
                const float* __restrict__ E1, const float* __restrict__ F1,
                const float* __restrict__ Fo, const float* __restrict__ S,
                const half8* __restrict__ PB2, const half8* __restrict__ PB3,
                const half8* __restrict__ PO1, const half8* __restrict__ PO2,
                float* __restrict__ out)
{
    __shared__ char act[2][MBLK * 512];   // 2 x 32 KB f16 activations
    __shared__ float sred[8][64];         // cross-wave partial sums

    const int t    = threadIdx.x;
    const int lane = t & 63;
    const int w    = t >> 6;           // 0..7
    const int p0   = blockIdx.x * MBLK;
    const int lr   = lane & 15;
    const int lq   = lane >> 4;

    const int b0 = p0 / NE;
    const int r0 = p0 - b0 * NE;

    // Preload all per-column constants once (off the critical path).
    const int nA = w * 16 + lq * 4;          // ntj = 0 (tile w, < 8)
    const int nB = (w + 8) * 16 + lq * 4;    // ntj = 1 (tile w+8)
    f4 bmb2[2], bmb3[2], bob2[2], wv3[2];
    bmb2[0] = *(const f4*)&mb2[nA];  bmb2[1] = *(const f4*)&mb2[nB];
    bmb3[0] = *(const f4*)&mb3[nA];
    bmb3[1] = (w < 6) ? *(const f4*)&mb3[nB] : (f4){0.f, 0.f, 0.f, 0.f};
    bob2[0] = *(const f4*)&ob2[nA];  bob2[1] = *(const f4*)&ob2[nB];
    wv3[0]  = *(const f4*)&oW3[nA];  wv3[1]  = *(const f4*)&oW3[nB];

    // ---- Phase A: h1 = silu(E1[e] + F1[b])  -> act0 ----
    {
        #pragma unroll
        for (int i = 0; i < 4; ++i) {
            int c   = i * 512 + t;
            int row = c >> 5;
            int c0  = (c & 31) * 8;
            int e = r0 + row;
            int b = b0;
            if (e >= NE) { e -= NE; b += 1; }
            const f4* ep = (const f4*)&E1[e * HID + c0];
            const f4* fp = (const f4*)&F1[b * HID + c0];
            f4 e0 = ep[0], e1 = ep[1];
            f4 f0 = fp[0], f1 = fp[1];
            half8 hv;
            #pragma unroll
            for (int j = 0; j < 4; ++j) hv[j]     = (_Float16)silu_f(e0[j] + f0[j]);
            #pragma unroll
            for (int j = 0; j < 4; ++j) hv[4 + j] = (_Float16)silu_f(e1[j] + f1[j]);
            *(half8*)(act[0] + swz(row, c0 * 2)) = hv;
        }
    }
    __syncthreads();   // (1) h1 visible

    f4 acc[4][2];

    // ---- Phase B: h2 = silu(h1 @ mW2 + mb2)   [read act0 -> write act1] ----
    #pragma unroll
    for (int mt = 0; mt < 4; ++mt) { acc[mt][0] = bmb2[0]; acc[mt][1] = bmb2[1]; }
    mma_phase<8, true>(PB2, act[0], lane, w, acc);
    #pragma unroll
    for (int ntj = 0; ntj < 2; ++ntj) {
        int n0 = ntj ? nB : nA;
        #pragma unroll
        for (int mt = 0; mt < 4; ++mt) {
            int row = mt * 16 + lr;
            half4 hv;
            #pragma unroll
            for (int r = 0; r < 4; ++r)
                hv[r] = (_Float16)silu_f(acc[mt][ntj][r]);
            *(half4*)(act[1] + swz(row, n0 * 2)) = hv;
        }
    }
    __syncthreads();   // (2) h2 visible; everyone past B-reads of act0

    // ---- Phase C: g = h2 @ mW3 + mb3 ; invariant  [read act1 -> write act0] ----
    #pragma unroll
    for (int mt = 0; mt < 4; ++mt) { acc[mt][0] = bmb3[0]; acc[mt][1] = bmb3[1]; }
    if (w < 6) mma_phase<8, true >(PB3, act[1], lane, w, acc);
    else       mma_phase<8, false>(PB3, act[1], lane, w, acc);
    int bmt[4];
    #pragma unroll
    for (int mt = 0; mt < 4; ++mt)
        bmt[mt] = b0 + ((r0 + mt * 16 + lr) >= NE);
    f4 xh[4], sv[4], fo[4][2];
    #pragma unroll
    for (int mt = 0; mt < 4; ++mt)
        xh[mt] = *(const f4*)&h_abs[bmt[mt] * DIN + nA];
    if (w < 6) {
        #pragma unroll
        for (int mt = 0; mt < 4; ++mt)
            sv[mt] = *(const f4*)&S[bmt[mt] * 96 + nA];   // S idx for tile w+8 is nB-128 == nA
    }
    // Prefetch phase-D's Fo acc-init here (hides L2 latency under C epilogue).
    #pragma unroll
    for (int mt = 0; mt < 4; ++mt) {
        fo[mt][0] = *(const f4*)&Fo[bmt[mt] * HID + nA];
        fo[mt][1] = *(const f4*)&Fo[bmt[mt] * HID + nB];
    }
    {
        // ntj=0: tile w (<8) -> scalar passthrough path, always.
        #pragma unroll
        for (int mt = 0; mt < 4; ++mt) {
            int row = mt * 16 + lr;
            half4 hv;
            #pragma unroll
            for (int r = 0; r < 4; ++r)
                hv[r] = (_Float16)(xh[mt][r] * acc[mt][0][r]);
            *(half4*)(act[0] + swz(row, nA * 2)) = hv;
        }
        // ntj=1: tile w+8 (exists iff w<6) -> L2-norm path.
        if (w < 6) {
            #pragma unroll
            for (int mt = 0; mt < 4; ++mt) {
                int row = mt * 16 + lr;
                half4 hv;
                #pragma unroll
                for (int r = 0; r < 4; ++r) {
                    float g = acc[mt][1][r];
                    hv[r] = (_Float16)__builtin_amdgcn_sqrtf(g * g * sv[mt][r] + 1e-8f);
                }
                *(half4*)(act[0] + swz(row, nB * 2)) = hv;
            }
        }
    }
    __syncthreads();   // (3) inv visible; everyone past C-reads of act1

    // ---- Phase D: o1 = silu(inv @ oW1[0:224] + Fo[b])  [read act0 -> write act1] ----
    #pragma unroll
    for (int mt = 0; mt < 4; ++mt) { acc[mt][0] = fo[mt][0]; acc[mt][1] = fo[mt][1]; }
    mma_phase<7, true>(PO1, act[0], lane, w, acc);
    #pragma unroll
    for (int ntj = 0; ntj < 2; ++ntj) {
        int n0 = ntj ? nB : nA;
        #pragma unroll
        for (int mt = 0; mt < 4; ++mt) {
            int row = mt * 16 + lr;
            half4 hv;
            #pragma unroll
            for (int r = 0; r < 4; ++r)
                hv[r] = (_Float16)silu_f(acc[mt][ntj][r]);
            *(half4*)(act[1] + swz(row, n0 * 2)) = hv;
        }
    }
    __syncthreads();   // (4) o1 visible

    // ---- Phase E+F fused: out[p] = silu(o1 @ oW2 + ob2) . oW3 + ob3 ----
    #pragma unroll
    for (int mt = 0; mt < 4; ++mt) { acc[mt][0] = bob2[0]; acc[mt][1] = bob2[1]; }
    mma_phase<8, true>(PO2, act[1], lane, w, acc);
    {
        float partial[4] = {0.f, 0.f, 0.f, 0.f};
        #pragma unroll
        for (int ntj = 0; ntj < 2; ++ntj) {
            #pragma unroll
            for (int mt = 0; mt < 4; ++mt)
                #pragma unroll
                for (int r = 0; r < 4; ++r)
                    partial[mt] += silu_f(acc[mt][ntj][r]) * wv3[ntj][r];
        }
        #pragma unroll
        for (int mt = 0; mt < 4; ++mt) {
            float s = partial[mt];
            s += __shfl_xor(s, 16, 64);
            s += __shfl_xor(s, 32, 64);
            if (lq == 0) sred[w][mt * 16 + lr] = s;
        }
    }
    __syncthreads();   // (5) sred visible
    if (t < 64) {
        float s = ob3[0];
        #pragma unroll
        for (int ww = 0; ww < 8; ++ww) s += sred[ww][t];
        out[p0 + t] = s;
    }
}

extern "C" void kernel_launch(void* const* d_in, const int* in_sizes, int n_in,
                              void* d_out, int out_size, void* d_ws, size_t ws_size,
                              hipStream_t stream) {
    const float* h_abs  = (const float*)d_in[0];
    const float* e_feat = (const float*)d_in[1];
    const float* field  = (const float*)d_in[2];
    const float* mW1 = (const float*)d_in[3];
    const float* mb1 = (const float*)d_in[4];
    const float* mW2 = (const float*)d_in[5];
    const float* mb2 = (const float*)d_in[6];
    const float* mW3 = (const float*)d_in[7];
    const float* mb3 = (const float*)d_in[8];
    const float* oW1 = (const float*)d_in[9];
    const float* ob1 = (const float*)d_in[10];
    const float* oW2 = (const float*)d_in[11];
    const float* ob2 = (const float*)d_in[12];
    const float* oW3 = (const float*)d_in[13];
    const float* ob3 = (const float*)d_in[14];
    float* out = (float*)d_out;

    // Workspace layout
    float* ws = (float*)d_ws;
    float* E1 = ws;                      // 400*256 = 102400 f
    float* F1 = E1 + NE * HID;           // 65536 f
    float* Fo = F1 + BB * HID;           // 65536 f
    float* S  = Fo + BB * HID;           // 24576 f
    _Float16* PB2 = (_Float16*)(S + BB * 96);   // 16*8*64*8 = 65536 h
    _Float16* PB3 = PB2 + 16 * 8 * 64 * 8;      // 14*8*64*8 = 57344 h
    _Float16* PO1 = PB3 + 14 * 8 * 64 * 8;      // 16*7*64*8 = 57344 h
    _Float16* PO2 = PO1 + 16 * 7 * 64 * 8;      // 16*8*64*8 = 65536 h

    precompute_kernel<<<NE + 3 * BB, 256, 0, stream>>>(
        h_abs, e_feat, field, mW1, mb1, oW1, ob1, E1, F1, Fo, S);

    pack_weights<<<480, 64, 0, stream>>>(
        mW2, mW3, oW1, oW2, PB2, PB3, PO1, PO2);

    fused_mfma<<<NBLK, 512, 0, stream>>>(
        h_abs, mb2, mb3, ob2, oW3, ob3,
        E1, F1, Fo, S,
        (const half8*)PB2, (const half8*)PB3, (const half8*)PO1, (const half8*)PO2,
        out);
}